// Round 2
// baseline (825.881 us; speedup 1.0000x reference)
//
#include <hip/hip_runtime.h>
#include <hip/hip_bf16.h>
#include <math.h>

#define B_   8
#define G_   1024
#define M_   8
#define N_   2048
#define RBF_ 50
#define H_   128
#define PP_  28      // i<j pairs of 8
#define RPAD 52      // RBF padded to multiple of 4
#define RC_  13      // RPAD/4

// ---- workspace layout (in floats) ----
#define OFF_WLT  0
#define SZ_WT    (PP_*RC_*H_*4)            // 186368
#define OFF_WRT  (OFF_WLT + SZ_WT)
#define OFF_XC   (OFF_WRT + SZ_WT)         // 372736
#define SZ_XC    (B_*G_*M_*3)              // 196608
#define OFF_ATT  (OFF_XC + SZ_XC)          // 569344  (layout [b][g][h])
#define SZ_ATT   (B_*H_*G_)                // 1048576
#define OFF_PART (OFF_ATT + SZ_ATT)        // 1617920
#define SZ_PART  (B_*8*H_*2)               // 16384

// ExpNormal constants: means = linspace(exp(-5),1,50); beta = (2/50*(1-exp(-5)))^-2
#define M0_   0.006737946999085467f
#define STEP_ 0.020270858224508f           // (1-M0)/49
#define BETA_ 633.5087862829640f
// recurrence: sm_{r+1} = sm_r * ratio_r ; ratio_{r+1} = ratio_r * BC_
// ratio_0 = exp(2*BETA*STEP*(e-M0) - BETA*STEP^2);  BC_ = exp(-2*BETA*STEP^2)
#define C2_   25.68448448181152f           // 2*BETA*STEP
#define C3_   0.26031300425529f            // BETA*STEP^2
#define BC_   0.59416621404589f            // exp(-2*BETA*STEP^2)

__device__ const int c_pi[28] = {0,0,0,0,0,0,0,1,1,1,1,1,1,2,2,2,2,2,3,3,3,3,4,4,4,5,5,6};
__device__ const int c_pj[28] = {1,2,3,4,5,6,7,2,3,4,5,6,7,3,4,5,6,7,4,5,6,7,5,6,7,6,7,7};

// K0: fold (i,j)-(j,i) weight pairs, transpose to [pp][rc][h][4]; r>=50 -> 0
// (zeros there make the recurrence tail in k_main harmless).
__global__ __launch_bounds__(256) void k_fold(const float* __restrict__ Wl,
                                              const float* __restrict__ Wr,
                                              float* __restrict__ ws) {
    int idx = blockIdx.x * 256 + threadIdx.x;
    int c = idx & 3;       int t = idx >> 2;
    int h = t & 127;       t >>= 7;
    int rc = t % 13;       t /= 13;
    int pp = t % 28;       int side = t / 28;
    if (side >= 2) return;
    int r = rc * 4 + c;
    const float* src = side ? Wr : Wl;
    float v = 0.f;
    if (r < 50) {
        int i = c_pi[pp], j = c_pj[pp];
        v = src[h*3200 + (i*8 + j)*50 + r] - src[h*3200 + (j*8 + i)*50 + r];
    }
    float* dst = ws + (side ? OFF_WRT : OFF_WLT);
    dst[((pp*13 + rc)*128 + h)*4 + c] = v;
}

// K1: xc[b,row,d] = sum_n W_map[row,n] * x[b,n,d]   (row = g*8+m)
// rows on lanes (each lane streams its OWN row contiguously -> every HBM
// byte used); n-slice index derived from blockIdx ONLY so x addresses are
// provably wave-uniform -> scalar (s_load) x reads, zero VALU cost.
// 16 n-slices combined via fp32 atomics (xc memset to 0 first).
__global__ __launch_bounds__(256) void k_xc(const float* __restrict__ x,
                                            const float* __restrict__ Wm,
                                            float* __restrict__ ws) {
    float* xc = ws + OFF_XC;
    int rg = blockIdx.x >> 4;                 // 32 row groups of 256 rows
    int ns = blockIdx.x & 15;                 // n-slice (uniform)
    int row = rg * 256 + threadIdx.x;
    int n0 = ns * 128;
    float acc[24];
#pragma unroll
    for (int c = 0; c < 24; ++c) acc[c] = 0.f;
    const float* wrow = Wm + (size_t)row * 2048 + n0;
    for (int k = 0; k < 32; ++k) {
        float4 w4 = *(const float4*)(wrow + k * 4);
#pragma unroll
        for (int j = 0; j < 4; ++j) {
            float wk = (j == 0) ? w4.x : (j == 1) ? w4.y : (j == 2) ? w4.z : w4.w;
            const float* xp = x + (size_t)(n0 + k*4 + j) * 3;   // uniform addr
#pragma unroll
            for (int bb = 0; bb < 8; ++bb) {
                acc[bb*3+0] += wk * xp[bb*6144 + 0];
                acc[bb*3+1] += wk * xp[bb*6144 + 1];
                acc[bb*3+2] += wk * xp[bb*6144 + 2];
            }
        }
    }
#pragma unroll
    for (int bb = 0; bb < 8; ++bb)
#pragma unroll
        for (int d = 0; d < 3; ++d)
            atomicAdd(&xc[(size_t)bb*24576 + row*3 + d], acc[bb*3+d]);
}

// K2: fused main. Block = 128 threads (2 waves) = 8 (b,g) pairs.
// Phase 1: build sm[slot=t*28+pp][52] via the geometric recurrence
// (2 muls per r instead of expf) + delta in LDS.
// Phase 2: thread = h (no h-replication -> weight traffic halved vs r1);
// t_tile=8: each weight float4 feeds 8 pairs. LDS sm reads are same-address
// broadcasts with all (t,rc) offsets as immediates on one base register.
// att stored [b][g][h] -> lane-contiguous stores.
__global__ __launch_bounds__(128, 2) void k_main(float* __restrict__ ws) {
    __shared__ float  sm_s[224 * RPAD];   // 46592 B
    __shared__ float4 dlt_s[224];         //  3584 B
    const float* xc = ws + OFF_XC;
    const float4* WLT = (const float4*)(ws + OFF_WLT);
    const float4* WRT = (const float4*)(ws + OFF_WRT);
    float* att = ws + OFF_ATT;

    int tid = threadIdx.x;
    int p0 = blockIdx.x * 8;
    int b  = p0 >> 10;
    int g0 = p0 & 1023;

    for (int slot = tid; slot < 224; slot += 128) {
        int t = slot / 28, pp = slot - t * 28;
        int i = c_pi[pp], j = c_pj[pp];
        const float* xp = xc + (size_t)(b*8192 + (g0 + t)*8) * 3;
        float dx = xp[j*3+0] - xp[i*3+0];
        float dy = xp[j*3+1] - xp[i*3+1];
        float dz = xp[j*3+2] - xp[i*3+2];
        float dn = sqrtf(dx*dx + dy*dy + dz*dz + 1e-5f);
        dlt_s[slot] = make_float4(dx, dy, dz, 0.f);
        float pref = 0.f;
        if (dn < 5.0f) pref = 0.5f * (cosf(dn * 0.62831853071795865f) + 1.0f);
        float dinv = dn + 1e-5f;
        pref /= (dinv * dinv);
        float e  = expf(-dn);
        float d0 = e - M0_;
        float sm    = pref * expf(-BETA_ * d0 * d0);   // sm at r=0
        float ratio = expf(C2_ * d0 - C3_);            // ratio_0
#pragma unroll
        for (int rc = 0; rc < 13; ++rc) {
            float4 v;
            v.x = sm; sm *= ratio; ratio *= BC_;
            v.y = sm; sm *= ratio; ratio *= BC_;
            v.z = sm; sm *= ratio; ratio *= BC_;
            v.w = sm; sm *= ratio; ratio *= BC_;
            *(float4*)&sm_s[slot * RPAD + rc * 4] = v;   // r>=50 tail: finite,
        }                                                 // hits zero weights
    }
    __syncthreads();

    float aLx[8], aLy[8], aLz[8], aRx[8], aRy[8], aRz[8];
#pragma unroll
    for (int t = 0; t < 8; ++t) { aLx[t]=aLy[t]=aLz[t]=0.f; aRx[t]=aRy[t]=aRz[t]=0.f; }

    for (int pp = 0; pp < 28; ++pp) {
        float Al[8], Ar[8];
#pragma unroll
        for (int t = 0; t < 8; ++t) { Al[t] = 0.f; Ar[t] = 0.f; }
#pragma unroll
        for (int rc = 0; rc < 13; ++rc) {
            float4 wl = WLT[(pp*13 + rc)*128 + tid];   // coalesced across h
            float4 wr = WRT[(pp*13 + rc)*128 + tid];
#pragma unroll
            for (int t = 0; t < 8; ++t) {
                const float4 s = *(const float4*)&sm_s[(t*28 + pp)*RPAD + rc*4];
                Al[t] += wl.x*s.x + wl.y*s.y + wl.z*s.z + wl.w*s.w;
                Ar[t] += wr.x*s.x + wr.y*s.y + wr.z*s.z + wr.w*s.w;
            }
        }
#pragma unroll
        for (int t = 0; t < 8; ++t) {
            float4 dl = dlt_s[t*28 + pp];
            aLx[t] += Al[t]*dl.x; aLy[t] += Al[t]*dl.y; aLz[t] += Al[t]*dl.z;
            aRx[t] += Ar[t]*dl.x; aRy[t] += Ar[t]*dl.y; aRz[t] += Ar[t]*dl.z;
        }
    }
#pragma unroll
    for (int t = 0; t < 8; ++t) {
        float v = aLx[t]*aRx[t] + aLy[t]*aRy[t] + aLz[t]*aRz[t] + 1e-5f;
        att[(size_t)(b*1024 + g0 + t)*128 + tid] = v;   // [b][g][h] coalesced
    }
}

// K3: partial online logsumexp over g. Grid 64 = (b, gblk); att is [b][g][h]
// so lanes (consecutive h) read consecutive floats -> fully coalesced.
__global__ __launch_bounds__(256) void k_lse(float* __restrict__ ws) {
    const float* att = ws + OFF_ATT;
    float* part = ws + OFF_PART;
    int blk = blockIdx.x;
    int b = blk >> 3, gblk = blk & 7;
    int tid = threadIdx.x;
    int h = tid & 127, gh = tid >> 7;
    const float* p = att + ((size_t)(b*1024 + gblk*128 + gh*64))*128 + h;
    float m = -1e30f, s = 0.f;
    for (int q = 0; q < 64; ++q) {
        float v = p[(size_t)q * 128];
        float nm = fmaxf(m, v);
        s = s * expf(m - nm) + expf(v - nm);
        m = nm;
    }
    __shared__ float mm[256], ss[256];
    mm[tid] = m; ss[tid] = s;
    __syncthreads();
    if (gh == 0) {
        float m2 = mm[tid + 128], s2 = ss[tid + 128];
        float Mv = fmaxf(m, m2);
        float Sv = s * expf(m - Mv) + s2 * expf(m2 - Mv);
        *(float2*)&part[((size_t)(b*8 + gblk)*128 + h)*2] = make_float2(Mv, Sv);
    }
}

// K4: combine partials -> lse[b][h], then fc1+silu+fc2 -> out[b].
__global__ __launch_bounds__(128) void k_mlp(const float* __restrict__ ws,
                                             const float* __restrict__ f1w,
                                             const float* __restrict__ f1b,
                                             const float* __restrict__ f2w,
                                             const float* __restrict__ f2b,
                                             float* __restrict__ out) {
    const float* part = ws + OFF_PART;
    int b = blockIdx.x, h = threadIdx.x;
    float ms[8], sv[8], Mv = -1e30f;
#pragma unroll
    for (int k = 0; k < 8; ++k) {
        float2 v = *(const float2*)&part[((size_t)(b*8 + k)*128 + h)*2];
        ms[k] = v.x; sv[k] = v.y;
        Mv = fmaxf(Mv, v.x);
    }
    float Sv = 0.f;
#pragma unroll
    for (int k = 0; k < 8; ++k) Sv += sv[k] * expf(ms[k] - Mv);
    float lse = Mv + logf(Sv);
    __shared__ float ls[128];
    ls[h] = lse;
    __syncthreads();
    float acc = f1b[h];
    for (int k = 0; k < 128; ++k) acc += f1w[h*128 + k] * ls[k];
    float v = acc / (1.f + expf(-acc));     // silu
    __shared__ float red[128];
    red[h] = v * f2w[h];
    __syncthreads();
    for (int st = 64; st > 0; st >>= 1) {
        if (h < st) red[h] += red[h + st];
        __syncthreads();
    }
    if (h == 0) out[b] = red[0] + f2b[0];
}

extern "C" void kernel_launch(void* const* d_in, const int* in_sizes, int n_in,
                              void* d_out, int out_size, void* d_ws, size_t ws_size,
                              hipStream_t stream) {
    const float* x   = (const float*)d_in[0];
    const float* Wm  = (const float*)d_in[1];
    const float* Wl  = (const float*)d_in[2];
    const float* Wr  = (const float*)d_in[3];
    const float* f1w = (const float*)d_in[4];
    const float* f1b = (const float*)d_in[5];
    const float* f2w = (const float*)d_in[6];
    const float* f2b = (const float*)d_in[7];
    float* ws  = (float*)d_ws;
    float* out = (float*)d_out;

    hipMemsetAsync(ws + OFF_XC, 0, SZ_XC * sizeof(float), stream);

    k_fold<<<1456, 256, 0, stream>>>(Wl, Wr, ws);
    k_xc  <<<512,  256, 0, stream>>>(x, Wm, ws);
    k_main<<<1024, 128, 0, stream>>>(ws);
    k_lse <<<64,   256, 0, stream>>>(ws);
    k_mlp <<<8,    128, 0, stream>>>(ws, f1w, f1b, f2w, f2b, out);
}

// Round 3
// 389.669 us; speedup vs baseline: 2.1194x; 2.1194x over previous
//
#include <hip/hip_runtime.h>
#include <hip/hip_bf16.h>
#include <math.h>

#define B_   8
#define G_   1024
#define M_   8
#define N_   2048
#define RBF_ 50
#define H_   128
#define PP_  28      // i<j pairs of 8
#define RPAD 52      // RBF padded to multiple of 4
#define RC_  13      // RPAD/4

// ---- workspace layout (in floats) ----
#define OFF_W    0                          // folded weights [pp][rc][2][128]
#define SZ_W     (PP_*RC_*2*H_)             // 93184 float4 slots -> 372736 floats
#define OFF_XC   (SZ_W*4)                   // 372736
#define SZ_XC    (B_*G_*M_*3)               // 196608
#define OFF_ATT  (OFF_XC + SZ_XC)           // 569344  (layout [b][g][h])
#define SZ_ATT   (B_*H_*G_)                 // 1048576
#define OFF_PART (OFF_ATT + SZ_ATT)         // 1617920
#define SZ_PART  (B_*8*H_*2)                // 16384

// ExpNormal constants: means = linspace(exp(-5),1,50); beta = (2/50*(1-exp(-5)))^-2
#define M0_   0.006737946999085467f
#define BETA_ 633.5087862829640f
// recurrence: sm_{r+1} = sm_r * ratio_r ; ratio_{r+1} = ratio_r * BC_
#define C2_   25.68448448181152f           // 2*BETA*STEP
#define C3_   0.26031300425529f            // BETA*STEP^2
#define BC_   0.59416621404589f            // exp(-2*BETA*STEP^2)

__device__ const int c_pi[28] = {0,0,0,0,0,0,0,1,1,1,1,1,1,2,2,2,2,2,3,3,3,3,4,4,4,5,5,6};
__device__ const int c_pj[28] = {1,2,3,4,5,6,7,2,3,4,5,6,7,3,4,5,6,7,4,5,6,7,5,6,7,6,7,7};

// K0: fold (i,j)-(j,i) weight pairs, layout [pp][rc][side][h] so k_main's
// wl/wr loads share one address register (side stride 2048 B = imm offset).
__global__ __launch_bounds__(256) void k_fold(const float* __restrict__ Wl,
                                              const float* __restrict__ Wr,
                                              float* __restrict__ ws) {
    int idx = blockIdx.x * 256 + threadIdx.x;
    int c = idx & 3;       int t = idx >> 2;
    int h = t & 127;       t >>= 7;
    int rc = t % 13;       t /= 13;
    int pp = t % 28;       int side = t / 28;
    if (side >= 2) return;
    int r = rc * 4 + c;
    const float* src = side ? Wr : Wl;
    float v = 0.f;
    if (r < 50) {
        int i = c_pi[pp], j = c_pj[pp];
        v = src[h*3200 + (i*8 + j)*50 + r] - src[h*3200 + (j*8 + i)*50 + r];
    }
    ws[((((pp*13 + rc)*2 + side)*128) + h)*4 + c] = v;
}

// K1: xc[b,row,d] = sum_n W_map[row,n] * x[b,n,d]   (row = g*8+m)
__global__ __launch_bounds__(256) void k_xc(const float* __restrict__ x,
                                            const float* __restrict__ Wm,
                                            float* __restrict__ ws) {
    float* xc = ws + OFF_XC;
    int rg = blockIdx.x >> 4;                 // 32 row groups of 256 rows
    int ns = blockIdx.x & 15;                 // n-slice (uniform)
    int row = rg * 256 + threadIdx.x;
    int n0 = ns * 128;
    float acc[24];
#pragma unroll
    for (int c = 0; c < 24; ++c) acc[c] = 0.f;
    const float* wrow = Wm + (size_t)row * 2048 + n0;
    for (int k = 0; k < 32; ++k) {
        float4 w4 = *(const float4*)(wrow + k * 4);
#pragma unroll
        for (int j = 0; j < 4; ++j) {
            float wk = (j == 0) ? w4.x : (j == 1) ? w4.y : (j == 2) ? w4.z : w4.w;
            const float* xp = x + (size_t)(n0 + k*4 + j) * 3;   // uniform addr
#pragma unroll
            for (int bb = 0; bb < 8; ++bb) {
                acc[bb*3+0] += wk * xp[bb*6144 + 0];
                acc[bb*3+1] += wk * xp[bb*6144 + 1];
                acc[bb*3+2] += wk * xp[bb*6144 + 2];
            }
        }
    }
#pragma unroll
    for (int bb = 0; bb < 8; ++bb)
#pragma unroll
        for (int d = 0; d < 3; ++d)
            atomicAdd(&xc[(size_t)bb*24576 + row*3 + d], acc[bb*3+d]);
}

// Accumulate rc chunk [LO,HI) for one pp into Al/Ar (t=8 pairs).
// Chunk size <=4 keeps in-flight weight loads to 8 float4 = 32 VGPRs.
template<int LO, int HI>
__device__ __forceinline__ void accum_chunk(const float4* __restrict__ W4,
                                            const float* __restrict__ sm_s,
                                            int pp, int h,
                                            float Al[8], float Ar[8]) {
    float4 wl[HI-LO], wr[HI-LO];
#pragma unroll
    for (int u = 0; u < HI-LO; ++u) {
        int base = ((pp*13 + LO + u)*2)*128 + h;
        wl[u] = W4[base];
        wr[u] = W4[base + 128];
    }
#pragma unroll
    for (int u = 0; u < HI-LO; ++u) {
#pragma unroll
        for (int t = 0; t < 8; ++t) {
            const float4 s = *(const float4*)&sm_s[(t*28 + pp)*RPAD + (LO+u)*4];
            Al[t] += wl[u].x*s.x + wl[u].y*s.y + wl[u].z*s.z + wl[u].w*s.w;
            Ar[t] += wr[u].x*s.x + wr[u].y*s.y + wr[u].z*s.z + wr[u].w*s.w;
        }
    }
}

// K2: fused main. Block = 256 threads (4 waves) = 8 (b,g) pairs.
// Phase 1: 224 threads build sm[slot][52] (geometric recurrence) + delta.
// Phase 2: group = tid>>7 splits the rc range (0..6 | 7..12); each thread
// owns h = tid&127 and accumulates partial aL/aR over all pp, t=8 pairs.
// Phase 3: group1 partials through LDS (reusing sm buffer), group0 combines,
// computes att = <left,right>+1e-5, stores [b][g][h] coalesced.
__global__ __launch_bounds__(256, 1) void k_main(float* __restrict__ ws) {
    __shared__ float  sm_s[224 * RPAD];   // 46592 B (reused for partials)
    __shared__ float4 dlt_s[224];         //  3584 B
    const float* xc = ws + OFF_XC;
    const float4* W4 = (const float4*)(ws + OFF_W);
    float* att = ws + OFF_ATT;

    int tid = threadIdx.x;
    int p0 = blockIdx.x * 8;
    int b  = p0 >> 10;
    int g0 = p0 & 1023;

    if (tid < 224) {
        int slot = tid;
        int t = slot / 28, pp = slot - t * 28;
        int i = c_pi[pp], j = c_pj[pp];
        const float* xp = xc + (size_t)(b*8192 + (g0 + t)*8) * 3;
        float dx = xp[j*3+0] - xp[i*3+0];
        float dy = xp[j*3+1] - xp[i*3+1];
        float dz = xp[j*3+2] - xp[i*3+2];
        float dn = sqrtf(dx*dx + dy*dy + dz*dz + 1e-5f);
        dlt_s[slot] = make_float4(dx, dy, dz, 0.f);
        float pref = 0.f;
        if (dn < 5.0f) pref = 0.5f * (cosf(dn * 0.62831853071795865f) + 1.0f);
        float dinv = dn + 1e-5f;
        pref /= (dinv * dinv);
        float e  = expf(-dn);
        float d0 = e - M0_;
        float sm    = pref * expf(-BETA_ * d0 * d0);   // r=0
        float ratio = expf(C2_ * d0 - C3_);            // ratio_0
#pragma unroll
        for (int rc = 0; rc < 13; ++rc) {
            float4 v;
            v.x = sm; sm *= ratio; ratio *= BC_;
            v.y = sm; sm *= ratio; ratio *= BC_;
            v.z = sm; sm *= ratio; ratio *= BC_;
            v.w = sm; sm *= ratio; ratio *= BC_;
            *(float4*)&sm_s[slot * RPAD + rc * 4] = v;   // r>=50 tail: finite,
        }                                                 // hits zero weights
    }
    __syncthreads();

    int h = tid & 127, grp = tid >> 7;
    float aLx[8], aLy[8], aLz[8], aRx[8], aRy[8], aRz[8];
#pragma unroll
    for (int t = 0; t < 8; ++t) { aLx[t]=aLy[t]=aLz[t]=0.f; aRx[t]=aRy[t]=aRz[t]=0.f; }

#pragma unroll 1
    for (int pp = 0; pp < 28; ++pp) {
        float Al[8], Ar[8];
#pragma unroll
        for (int t = 0; t < 8; ++t) { Al[t] = 0.f; Ar[t] = 0.f; }
        if (grp == 0) {                        // rc 0..6
            accum_chunk<0,4>(W4, sm_s, pp, h, Al, Ar);
            accum_chunk<4,7>(W4, sm_s, pp, h, Al, Ar);
        } else {                               // rc 7..12
            accum_chunk<7,11>(W4, sm_s, pp, h, Al, Ar);
            accum_chunk<11,13>(W4, sm_s, pp, h, Al, Ar);
        }
#pragma unroll
        for (int t = 0; t < 8; ++t) {
            float4 dl = dlt_s[t*28 + pp];
            aLx[t] += Al[t]*dl.x; aLy[t] += Al[t]*dl.y; aLz[t] += Al[t]*dl.z;
            aRx[t] += Ar[t]*dl.x; aRy[t] += Ar[t]*dl.y; aRz[t] += Ar[t]*dl.z;
        }
    }

    __syncthreads();                 // sm_s dead; reuse for partials
    float* part_s = sm_s;            // [t][c][h] planes, stride-1 in h
    if (grp == 1) {
#pragma unroll
        for (int t = 0; t < 8; ++t) {
            part_s[(t*6 + 0)*128 + h] = aLx[t];
            part_s[(t*6 + 1)*128 + h] = aLy[t];
            part_s[(t*6 + 2)*128 + h] = aLz[t];
            part_s[(t*6 + 3)*128 + h] = aRx[t];
            part_s[(t*6 + 4)*128 + h] = aRy[t];
            part_s[(t*6 + 5)*128 + h] = aRz[t];
        }
    }
    __syncthreads();
    if (grp == 0) {
#pragma unroll
        for (int t = 0; t < 8; ++t) {
            float lx = aLx[t] + part_s[(t*6 + 0)*128 + h];
            float ly = aLy[t] + part_s[(t*6 + 1)*128 + h];
            float lz = aLz[t] + part_s[(t*6 + 2)*128 + h];
            float rx = aRx[t] + part_s[(t*6 + 3)*128 + h];
            float ry = aRy[t] + part_s[(t*6 + 4)*128 + h];
            float rz = aRz[t] + part_s[(t*6 + 5)*128 + h];
            att[(size_t)(b*1024 + g0 + t)*128 + h] = lx*rx + ly*ry + lz*rz + 1e-5f;
        }
    }
}

// K3: partial online logsumexp over g. att is [b][g][h] -> coalesced.
__global__ __launch_bounds__(256) void k_lse(float* __restrict__ ws) {
    const float* att = ws + OFF_ATT;
    float* part = ws + OFF_PART;
    int blk = blockIdx.x;
    int b = blk >> 3, gblk = blk & 7;
    int tid = threadIdx.x;
    int h = tid & 127, gh = tid >> 7;
    const float* p = att + ((size_t)(b*1024 + gblk*128 + gh*64))*128 + h;
    float m = -1e30f, s = 0.f;
    for (int q = 0; q < 64; ++q) {
        float v = p[(size_t)q * 128];
        float nm = fmaxf(m, v);
        s = s * expf(m - nm) + expf(v - nm);
        m = nm;
    }
    __shared__ float mm[256], ss[256];
    mm[tid] = m; ss[tid] = s;
    __syncthreads();
    if (gh == 0) {
        float m2 = mm[tid + 128], s2 = ss[tid + 128];
        float Mv = fmaxf(m, m2);
        float Sv = s * expf(m - Mv) + s2 * expf(m2 - Mv);
        *(float2*)&part[((size_t)(b*8 + gblk)*128 + h)*2] = make_float2(Mv, Sv);
    }
}

// K4: combine partials -> lse[b][h], then fc1+silu+fc2 -> out[b].
__global__ __launch_bounds__(128) void k_mlp(const float* __restrict__ ws,
                                             const float* __restrict__ f1w,
                                             const float* __restrict__ f1b,
                                             const float* __restrict__ f2w,
                                             const float* __restrict__ f2b,
                                             float* __restrict__ out) {
    const float* part = ws + OFF_PART;
    int b = blockIdx.x, h = threadIdx.x;
    float ms[8], sv[8], Mv = -1e30f;
#pragma unroll
    for (int k = 0; k < 8; ++k) {
        float2 v = *(const float2*)&part[((size_t)(b*8 + k)*128 + h)*2];
        ms[k] = v.x; sv[k] = v.y;
        Mv = fmaxf(Mv, v.x);
    }
    float Sv = 0.f;
#pragma unroll
    for (int k = 0; k < 8; ++k) Sv += sv[k] * expf(ms[k] - Mv);
    float lse = Mv + logf(Sv);
    __shared__ float ls[128];
    ls[h] = lse;
    __syncthreads();
    float acc = f1b[h];
    for (int k = 0; k < 128; ++k) acc += f1w[h*128 + k] * ls[k];
    float v = acc / (1.f + expf(-acc));     // silu
    __shared__ float red[128];
    red[h] = v * f2w[h];
    __syncthreads();
    for (int st = 64; st > 0; st >>= 1) {
        if (h < st) red[h] += red[h + st];
        __syncthreads();
    }
    if (h == 0) out[b] = red[0] + f2b[0];
}

extern "C" void kernel_launch(void* const* d_in, const int* in_sizes, int n_in,
                              void* d_out, int out_size, void* d_ws, size_t ws_size,
                              hipStream_t stream) {
    const float* x   = (const float*)d_in[0];
    const float* Wm  = (const float*)d_in[1];
    const float* Wl  = (const float*)d_in[2];
    const float* Wr  = (const float*)d_in[3];
    const float* f1w = (const float*)d_in[4];
    const float* f1b = (const float*)d_in[5];
    const float* f2w = (const float*)d_in[6];
    const float* f2b = (const float*)d_in[7];
    float* ws  = (float*)d_ws;
    float* out = (float*)d_out;

    hipMemsetAsync(ws + OFF_XC, 0, SZ_XC * sizeof(float), stream);

    k_fold<<<1456, 256, 0, stream>>>(Wl, Wr, ws);
    k_xc  <<<512,  256, 0, stream>>>(x, Wm, ws);
    k_main<<<1024, 256, 0, stream>>>(ws);
    k_lse <<<64,   256, 0, stream>>>(ws);
    k_mlp <<<8,    128, 0, stream>>>(ws, f1w, f1b, f2w, f2b, out);
}

// Round 4
// 224.835 us; speedup vs baseline: 3.6733x; 1.7331x over previous
//
#include <hip/hip_runtime.h>
#include <hip/hip_bf16.h>
#include <math.h>

#define B_   8
#define G_   1024
#define M_   8
#define N_   2048
#define RBF_ 50
#define H_   128
#define PP_  28      // i<j pairs of 8
#define RPP  64      // r padded per pp (2 MFMA K-steps); r>=50 -> A holds 0
#define KTOT (PP_*RPP)          // 1792
#define KSTEPS (KTOT/32)        // 56
#define TPB  32      // (b,g) pairs per k_main block -> N=96 cols

// ---- workspace layout (in floats) ----
// A: bf16 fragment-ordered weights [kstep(56)][mtile(16)][lane(64)][8 bf16]
#define OFF_A    0
#define SZ_A     (KSTEPS*16*64*8/2)        // 229376 floats (917504 B)
#define OFF_XC   (OFF_A + SZ_A)            // 229376
#define SZ_XC    (B_*G_*M_*3)              // 196608
#define OFF_ATT  (OFF_XC + SZ_XC)          // 425984  (layout [b][g][h])
#define SZ_ATT   (B_*H_*G_)                // 1048576
#define OFF_PART (OFF_ATT + SZ_ATT)        // 1474560
#define SZ_PART  (B_*8*H_*2)               // 16384

// ExpNormal constants: means = linspace(exp(-5),1,50); beta = (2/50*(1-exp(-5)))^-2
#define M0_   0.006737946999085467f
#define STEP_ 0.020270858224508f
#define BETA_ 633.5087862829640f
#define C2_   25.68448448181152f           // 2*BETA*STEP
#define C3_   0.26031300425529f            // BETA*STEP^2
#define BC_   0.59416621404589f            // exp(-2*BETA*STEP^2)

typedef __attribute__((ext_vector_type(8))) short s8v;   // 8 bf16 (4 VGPR)
typedef __attribute__((ext_vector_type(4))) float f4v;   // MFMA accum

__device__ const int c_pi[28] = {0,0,0,0,0,0,0,1,1,1,1,1,1,2,2,2,2,2,3,3,3,3,4,4,4,5,5,6};
__device__ const int c_pj[28] = {1,2,3,4,5,6,7,2,3,4,5,6,7,3,4,5,6,7,4,5,6,7,5,6,7,6,7,7};

__device__ __forceinline__ unsigned short f2bf(float f) {   // RNE f32->bf16
    unsigned int b = __float_as_uint(f);
    return (unsigned short)((b + 0x7FFFu + ((b >> 16) & 1u)) >> 16);
}

// K0: build A = folded weights in MFMA A-fragment order, bf16.
// Row = side*128+h (side 0=left,1=right); k = pp*64 + r, zero for r>=50.
// Fragment: lane holds row = mt*16 + (lane&15), k8 = kstep*32 + (lane>>4)*8.
// Thread t handles one lane-fragment (8 bf16 = 16B), store fully coalesced.
__global__ __launch_bounds__(256) void k_folda(const float* __restrict__ Wl,
                                               const float* __restrict__ Wr,
                                               float* __restrict__ ws) {
    int t = blockIdx.x * 256 + threadIdx.x;   // 57344 tasks
    int lane = t & 63;
    int mt = (t >> 6) & 15;
    int kstep = t >> 10;                      // 0..55
    int pp = kstep >> 1;
    int row = mt * 16 + (lane & 15);
    int side = row >> 7, h = row & 127;
    int r0 = (kstep & 1) * 32 + (lane >> 4) * 8;   // r within pp, 0..56
    int i = c_pi[pp], j = c_pj[pp];
    const float* src = side ? Wr : Wl;
    const float* pij = src + h * 3200 + (i * 8 + j) * 50;
    const float* pji = src + h * 3200 + (j * 8 + i) * 50;
    s8v v;
#pragma unroll
    for (int e = 0; e < 8; ++e) {
        int r = r0 + e;
        float f = (r < 50) ? (pij[r] - pji[r]) : 0.f;
        v[e] = (short)f2bf(f);
    }
    ((s8v*)(ws + OFF_A))[t] = v;
}

// K1: xc[b,row,d] = sum_n W_map[row,n] * x[b,n,d]   (row = g*8+m)
__global__ __launch_bounds__(256) void k_xc(const float* __restrict__ x,
                                            const float* __restrict__ Wm,
                                            float* __restrict__ ws) {
    float* xc = ws + OFF_XC;
    int rg = blockIdx.x >> 4;                 // 32 row groups of 256 rows
    int ns = blockIdx.x & 15;                 // n-slice (uniform)
    int row = rg * 256 + threadIdx.x;
    int n0 = ns * 128;
    float acc[24];
#pragma unroll
    for (int c = 0; c < 24; ++c) acc[c] = 0.f;
    const float* wrow = Wm + (size_t)row * 2048 + n0;
    for (int k = 0; k < 32; ++k) {
        float4 w4 = *(const float4*)(wrow + k * 4);
#pragma unroll
        for (int j = 0; j < 4; ++j) {
            float wk = (j == 0) ? w4.x : (j == 1) ? w4.y : (j == 2) ? w4.z : w4.w;
            const float* xp = x + (size_t)(n0 + k*4 + j) * 3;   // uniform addr
#pragma unroll
            for (int bb = 0; bb < 8; ++bb) {
                acc[bb*3+0] += wk * xp[bb*6144 + 0];
                acc[bb*3+1] += wk * xp[bb*6144 + 1];
                acc[bb*3+2] += wk * xp[bb*6144 + 2];
            }
        }
    }
#pragma unroll
    for (int bb = 0; bb < 8; ++bb)
#pragma unroll
        for (int d = 0; d < 3; ++d)
            atomicAdd(&xc[(size_t)bb*24576 + row*3 + d], acc[bb*3+d]);
}

// K2: MFMA main. Block = 256 threads (4 waves), 32 pairs, N=96 cols (pair*3+d).
// Per pp (K=64 = 2 K-steps): all threads build B-frags (sm recurrence x delta,
// bf16) into LDS; waves run 2ks x 6nt x 4mt mfma_f32_16x16x32_bf16 with
// A-frags prefetched from global (L2-resident). Epilogue pairs left/right
// via in-place LDS product (stride 97, conflict-free), emits att[b][g][h].
__global__ __launch_bounds__(256, 1) void k_main(float* __restrict__ ws) {
    __shared__ __align__(16) char smem[128 * 97 * 4];   // 49664 B
    s8v*   Bf = (s8v*)smem;          // B frags: [ks(2)][nt(6)][lane(64)] 16B
    float* P  = (float*)smem;        // epilogue: [row(128)][97]

    const float* xc = ws + OFF_XC;
    const s8v* A8 = (const s8v*)(ws + OFF_A);
    float* att = ws + OFF_ATT;

    int tid = threadIdx.x;
    int wave = tid >> 6, lane = tid & 63;
    int p0 = blockIdx.x * TPB;

    // builder role
    int pairL = tid >> 3;            // 0..31
    int sub = tid & 7;
    int rblk = sub >> 1;             // r-range [16*rblk, 16*rblk+16)
    int dh = sub & 1;                // 0 -> d{0,1}, 1 -> d{2}
    int pairG = p0 + pairL;
    int bb = pairG >> 10, gg = pairG & 1023;
    const float* xp = xc + ((size_t)bb * 8192 + gg * 8) * 3;

    // wave's M-tiles: mi 0,1 -> left 2w,2w+1 ; mi 2,3 -> right 2w+8,2w+9
    int mtile[4] = {2*wave, 2*wave+1, 2*wave+8, 2*wave+9};

    f4v acc[4][6];
#pragma unroll
    for (int mi = 0; mi < 4; ++mi)
#pragma unroll
        for (int nt = 0; nt < 6; ++nt) acc[mi][nt] = (f4v)0.f;

    for (int pp = 0; pp < 28; ++pp) {
        // A prefetch for this pp (consumed after the barrier -> latency hidden)
        s8v afr[2][4];
#pragma unroll
        for (int ksl = 0; ksl < 2; ++ksl)
#pragma unroll
            for (int mi = 0; mi < 4; ++mi)
                afr[ksl][mi] = A8[((pp*2 + ksl)*16 + mtile[mi])*64 + lane];

        // ---- B build ----
        int i = c_pi[pp], j = c_pj[pp];
        float dx = xp[j*3+0] - xp[i*3+0];
        float dy = xp[j*3+1] - xp[i*3+1];
        float dz = xp[j*3+2] - xp[i*3+2];
        float dn = sqrtf(dx*dx + dy*dy + dz*dz + 1e-5f);
        float pref = 0.f;
        if (dn < 5.0f) pref = 0.5f * (cosf(dn * 0.62831853071795865f) + 1.0f);
        float dinv = dn + 1e-5f;
        pref /= (dinv * dinv);
        float ex = expf(-dn);
        int r0 = rblk * 16;
        float d0 = ex - (M0_ + (float)r0 * STEP_);
        float sm    = pref * expf(-BETA_ * d0 * d0);
        float ratio = expf(C2_ * d0 - C3_);
        float smv[16];
#pragma unroll
        for (int q = 0; q < 16; ++q) { smv[q] = sm; sm *= ratio; ratio *= BC_; }

        float dd[2];
        int ndw;
        if (dh == 0) { dd[0] = dx; dd[1] = dy; ndw = 2; }
        else         { dd[0] = dz; dd[1] = 0.f; ndw = 1; }
#pragma unroll
        for (int w = 0; w < 2; ++w) {
            if (w >= ndw) break;
            int d = (dh == 0) ? w : 2;
            int col = pairL * 3 + d;
            int nt = col >> 4, cl = col & 15;
#pragma unroll
            for (int half = 0; half < 2; ++half) {
                int rb = r0 + half * 8;                 // 8-aligned
                int ks = rb >> 5;
                int lf = (((rb >> 3) & 3) << 4) | cl;
                s8v v;
#pragma unroll
                for (int e = 0; e < 8; ++e)
                    v[e] = (short)f2bf(smv[half*8 + e] * dd[w]);
                Bf[(ks*6 + nt)*64 + lf] = v;
            }
        }
        __syncthreads();

        // ---- MFMA ----
#pragma unroll
        for (int ksl = 0; ksl < 2; ++ksl)
#pragma unroll
            for (int nt = 0; nt < 6; ++nt) {
                s8v bfr = Bf[(ksl*6 + nt)*64 + lane];
#pragma unroll
                for (int mi = 0; mi < 4; ++mi)
                    acc[mi][nt] = __builtin_amdgcn_mfma_f32_16x16x32_bf16(
                        afr[ksl][mi], bfr, acc[mi][nt], 0, 0, 0);
            }
        __syncthreads();
    }

    // ---- epilogue: att[h,pair] = sum_d left*right + 1e-5 ----
    // step 1: write LEFT frags to P[row][col], stride 97
#pragma unroll
    for (int mi = 0; mi < 2; ++mi)
#pragma unroll
        for (int nt = 0; nt < 6; ++nt)
#pragma unroll
            for (int reg = 0; reg < 4; ++reg) {
                int row = mtile[mi]*16 + (lane >> 4)*4 + reg;
                int col = nt*16 + (lane & 15);
                P[row*97 + col] = acc[mi][nt][reg];
            }
    __syncthreads();
    // step 2: in-place multiply with RIGHT frags (same thread owns both addrs)
#pragma unroll
    for (int mi = 2; mi < 4; ++mi)
#pragma unroll
        for (int nt = 0; nt < 6; ++nt)
#pragma unroll
            for (int reg = 0; reg < 4; ++reg) {
                int row = (mtile[mi] - 8)*16 + (lane >> 4)*4 + reg;
                int col = nt*16 + (lane & 15);
                P[row*97 + col] *= acc[mi][nt][reg];
            }
    __syncthreads();
    // step 3: att = sum of 3 cols; coalesced store to att[(p0+pr)*128 + h]
    int h = tid & 127;
    int pr0 = (tid >> 7) * 16;
#pragma unroll
    for (int q = 0; q < 16; ++q) {
        int pr = pr0 + q;
        float a = P[h*97 + pr*3] + P[h*97 + pr*3 + 1] + P[h*97 + pr*3 + 2] + 1e-5f;
        att[(size_t)(p0 + pr) * 128 + h] = a;
    }
}

// K3: partial online logsumexp over g. att is [b][g][h] -> coalesced.
__global__ __launch_bounds__(256) void k_lse(float* __restrict__ ws) {
    const float* att = ws + OFF_ATT;
    float* part = ws + OFF_PART;
    int blk = blockIdx.x;
    int b = blk >> 3, gblk = blk & 7;
    int tid = threadIdx.x;
    int h = tid & 127, gh = tid >> 7;
    const float* p = att + ((size_t)(b*1024 + gblk*128 + gh*64))*128 + h;
    float m = -1e30f, s = 0.f;
    for (int q = 0; q < 64; ++q) {
        float v = p[(size_t)q * 128];
        float nm = fmaxf(m, v);
        s = s * expf(m - nm) + expf(v - nm);
        m = nm;
    }
    __shared__ float mm[256], ss[256];
    mm[tid] = m; ss[tid] = s;
    __syncthreads();
    if (gh == 0) {
        float m2 = mm[tid + 128], s2 = ss[tid + 128];
        float Mv = fmaxf(m, m2);
        float Sv = s * expf(m - Mv) + s2 * expf(m2 - Mv);
        *(float2*)&part[((size_t)(b*8 + gblk)*128 + h)*2] = make_float2(Mv, Sv);
    }
}

// K4: combine partials -> lse[b][h], then fc1+silu+fc2 -> out[b].
__global__ __launch_bounds__(128) void k_mlp(const float* __restrict__ ws,
                                             const float* __restrict__ f1w,
                                             const float* __restrict__ f1b,
                                             const float* __restrict__ f2w,
                                             const float* __restrict__ f2b,
                                             float* __restrict__ out) {
    const float* part = ws + OFF_PART;
    int b = blockIdx.x, h = threadIdx.x;
    float ms[8], sv[8], Mv = -1e30f;
#pragma unroll
    for (int k = 0; k < 8; ++k) {
        float2 v = *(const float2*)&part[((size_t)(b*8 + k)*128 + h)*2];
        ms[k] = v.x; sv[k] = v.y;
        Mv = fmaxf(Mv, v.x);
    }
    float Sv = 0.f;
#pragma unroll
    for (int k = 0; k < 8; ++k) Sv += sv[k] * expf(ms[k] - Mv);
    float lse = Mv + logf(Sv);
    __shared__ float ls[128];
    ls[h] = lse;
    __syncthreads();
    float acc = f1b[h];
    for (int k = 0; k < 128; ++k) acc += f1w[h*128 + k] * ls[k];
    float v = acc / (1.f + expf(-acc));     // silu
    __shared__ float red[128];
    red[h] = v * f2w[h];
    __syncthreads();
    for (int st = 64; st > 0; st >>= 1) {
        if (h < st) red[h] += red[h + st];
        __syncthreads();
    }
    if (h == 0) out[b] = red[0] + f2b[0];
}

extern "C" void kernel_launch(void* const* d_in, const int* in_sizes, int n_in,
                              void* d_out, int out_size, void* d_ws, size_t ws_size,
                              hipStream_t stream) {
    const float* x   = (const float*)d_in[0];
    const float* Wm  = (const float*)d_in[1];
    const float* Wl  = (const float*)d_in[2];
    const float* Wr  = (const float*)d_in[3];
    const float* f1w = (const float*)d_in[4];
    const float* f1b = (const float*)d_in[5];
    const float* f2w = (const float*)d_in[6];
    const float* f2b = (const float*)d_in[7];
    float* ws  = (float*)d_ws;
    float* out = (float*)d_out;

    hipMemsetAsync(ws + OFF_XC, 0, SZ_XC * sizeof(float), stream);

    k_folda<<<224, 256, 0, stream>>>(Wl, Wr, ws);
    k_xc   <<<512, 256, 0, stream>>>(x, Wm, ws);
    k_main <<<256, 256, 0, stream>>>(ws);
    k_lse  <<<64,  256, 0, stream>>>(ws);
    k_mlp  <<<8,   128, 0, stream>>>(ws, f1w, f1b, f2w, f2b, out);
}

// Round 5
// 224.063 us; speedup vs baseline: 3.6859x; 1.0034x over previous
//
#include <hip/hip_runtime.h>
#include <hip/hip_bf16.h>
#include <math.h>

#define B_   8
#define G_   1024
#define M_   8
#define N_   2048
#define RBF_ 50
#define H_   128
#define PP_  28      // i<j pairs of 8
#define RPP  64      // r padded per pp (2 MFMA K-steps); r>=50 -> A holds 0
#define KSTEPS (PP_*RPP/32)     // 56
#define TPB  32      // (b,g) pairs per k_main block -> N=96 cols

// ---- workspace layout (in floats) ----
#define OFF_A    0
#define SZ_A     (KSTEPS*16*64*8/2)        // 229376 floats (bf16 A frags)
#define OFF_XC   (OFF_A + SZ_A)            // 229376
#define SZ_XC    (B_*G_*M_*3)              // 196608
#define OFF_ATT  (OFF_XC + SZ_XC)          // 425984  (layout [b][g][h])
#define SZ_ATT   (B_*H_*G_)                // 1048576
#define OFF_PART (OFF_ATT + SZ_ATT)        // 1474560
#define SZ_PART  (B_*32*H_*2)              // 65536

// ExpNormal constants
#define M0_   0.006737946999085467f
#define STEP_ 0.020270858224508f
#define BETA_ 633.5087862829640f
#define C2_   25.68448448181152f           // 2*BETA*STEP
#define C3_   0.26031300425529f            // BETA*STEP^2
#define BC_   0.59416621404589f            // exp(-2*BETA*STEP^2)

typedef __attribute__((ext_vector_type(8))) short s8v;   // 8 bf16
typedef __attribute__((ext_vector_type(4))) float f4v;

// lgkmcnt-only barrier: LDS producer/consumer sync WITHOUT draining vmcnt,
// so global load streams survive across it (no global_load_lds used here).
#define LBAR() do { \
    asm volatile("s_waitcnt lgkmcnt(0)\n\ts_barrier" ::: "memory"); \
    __builtin_amdgcn_sched_barrier(0); \
} while (0)

__device__ const int c_pi[28] = {0,0,0,0,0,0,0,1,1,1,1,1,1,2,2,2,2,2,3,3,3,3,4,4,4,5,5,6};
__device__ const int c_pj[28] = {1,2,3,4,5,6,7,2,3,4,5,6,7,3,4,5,6,7,4,5,6,7,5,6,7,6,7,7};

__device__ __forceinline__ unsigned short f2bf(float f) {   // RNE f32->bf16
    unsigned int b = __float_as_uint(f);
    return (unsigned short)((b + 0x7FFFu + ((b >> 16) & 1u)) >> 16);
}

// K0: folded weights in MFMA A-fragment order, bf16 (unchanged from r4).
__global__ __launch_bounds__(256) void k_folda(const float* __restrict__ Wl,
                                               const float* __restrict__ Wr,
                                               float* __restrict__ ws) {
    int t = blockIdx.x * 256 + threadIdx.x;   // 57344 tasks
    int lane = t & 63;
    int mt = (t >> 6) & 15;
    int kstep = t >> 10;                      // 0..55
    int pp = kstep >> 1;
    int row = mt * 16 + (lane & 15);
    int side = row >> 7, h = row & 127;
    int r0 = (kstep & 1) * 32 + (lane >> 4) * 8;
    int i = c_pi[pp], j = c_pj[pp];
    const float* src = side ? Wr : Wl;
    const float* pij = src + h * 3200 + (i * 8 + j) * 50;
    const float* pji = src + h * 3200 + (j * 8 + i) * 50;
    s8v v;
#pragma unroll
    for (int e = 0; e < 8; ++e) {
        int r = r0 + e;
        float f = (r < 50) ? (pij[r] - pji[r]) : 0.f;
        v[e] = (short)f2bf(f);
    }
    ((s8v*)(ws + OFF_A))[t] = v;
}

// K1 v2: xc[b,row,d] = sum_n W_map[row,n]*x[b,n,d].
// 512 blocks x 16 rows (4 waves x 4 rows). x staged per 256-n chunk into LDS
// planes x_s[c4][n] (float4 of bd=c4*4+e); lane<->n so ds_read_b128 is
// lane-distributed. W: 16 coalesced dword streams/lane/chunk. lgkm-only
// barriers keep global loads in flight. Epilogue: wave-local LDS transpose
// reduce (no atomics, no global memset needed).
__global__ __launch_bounds__(256, 2) void k_xc(const float* __restrict__ x,
                                               const float* __restrict__ Wm,
                                               float* __restrict__ ws) {
    __shared__ float4 x_s[6][256];       // 24576 B
    __shared__ float  red[4][24][68];    // 26112 B
    float* xc = ws + OFF_XC;

    int tid = threadIdx.x;
    int wave = tid >> 6, lane = tid & 63;
    int rowbase = blockIdx.x * 16 + wave * 4;

    f4v acc[4][6];
#pragma unroll
    for (int r = 0; r < 4; ++r)
#pragma unroll
        for (int p = 0; p < 6; ++p) acc[r][p] = (f4v)0.f;

    // ---- stage chunk 0 ----
#pragma unroll
    for (int p = 0; p < 6; ++p) {
        int bd0 = p * 4;
        float4 v;
        v.x = x[(bd0/3)*6144     + tid*3 + (bd0%3)];
        v.y = x[((bd0+1)/3)*6144 + tid*3 + ((bd0+1)%3)];
        v.z = x[((bd0+2)/3)*6144 + tid*3 + ((bd0+2)%3)];
        v.w = x[((bd0+3)/3)*6144 + tid*3 + ((bd0+3)%3)];
        x_s[p][tid] = v;
    }
    LBAR();

#pragma unroll 1
    for (int nc = 0; nc < 8; ++nc) {
        int n0 = nc * 256;
        // prefetch next chunk's x into regs (issued before compute; consumed
        // after LBAR -> latency hidden under this chunk's FMAs)
        float4 pf[6];
        if (nc < 7) {
            int n1 = n0 + 256;
#pragma unroll
            for (int p = 0; p < 6; ++p) {
                int bd0 = p * 4;
                pf[p].x = x[(bd0/3)*6144     + (n1+tid)*3 + (bd0%3)];
                pf[p].y = x[((bd0+1)/3)*6144 + (n1+tid)*3 + ((bd0+1)%3)];
                pf[p].z = x[((bd0+2)/3)*6144 + (n1+tid)*3 + ((bd0+2)%3)];
                pf[p].w = x[((bd0+3)/3)*6144 + (n1+tid)*3 + ((bd0+3)%3)];
            }
        }
        // W loads: 4 rows x 4 sub-n, coalesced dwords, all issued up front
        float wv[4][4];
#pragma unroll
        for (int r = 0; r < 4; ++r) {
            const float* wrow = Wm + (size_t)(rowbase + r) * 2048 + n0 + lane;
#pragma unroll
            for (int k = 0; k < 4; ++k) wv[r][k] = wrow[k * 64];
        }
#pragma unroll
        for (int k = 0; k < 4; ++k) {
            int nn = k * 64 + lane;
#pragma unroll
            for (int p = 0; p < 6; ++p) {
                float4 xq = x_s[p][nn];
#pragma unroll
                for (int r = 0; r < 4; ++r) {
                    acc[r][p].x += wv[r][k] * xq.x;
                    acc[r][p].y += wv[r][k] * xq.y;
                    acc[r][p].z += wv[r][k] * xq.z;
                    acc[r][p].w += wv[r][k] * xq.w;
                }
            }
        }
        LBAR();                       // all reads of x_s done
        if (nc < 7) {
#pragma unroll
            for (int p = 0; p < 6; ++p) x_s[p][tid] = pf[p];
        }
        LBAR();                       // writes visible
    }

    // ---- wave-local transpose reduce: sum acc over 64 lanes ----
    int cc = lane;                    // candidate c = bd
#pragma unroll 1
    for (int r = 0; r < 4; ++r) {
#pragma unroll
        for (int p = 0; p < 6; ++p) {
            red[wave][p*4+0][lane] = acc[r][p].x;
            red[wave][p*4+1][lane] = acc[r][p].y;
            red[wave][p*4+2][lane] = acc[r][p].z;
            red[wave][p*4+3][lane] = acc[r][p].w;
        }
        if (cc < 24) {                // wave-local: no barrier needed
            float s = 0.f;
#pragma unroll
            for (int k = 0; k < 16; ++k) {
                float4 v = *(const float4*)&red[wave][cc][k*4];
                s += (v.x + v.y) + (v.z + v.w);
            }
            int row = rowbase + r;
            int b = cc / 3, d = cc - b * 3;
            xc[(size_t)b*24576 + row*3 + d] = s;
        }
    }
}

// K2: MFMA main, 8 waves (512 thr), 32 pairs, N=96. Wave w owns mtiles
// {w (left), w+8 (right)}. lgkm-only barriers keep A prefetch in flight.
__global__ __launch_bounds__(512, 1) void k_main(float* __restrict__ ws) {
    __shared__ __align__(16) char smem[128 * 97 * 4];   // 49664 B
    s8v*   Bf = (s8v*)smem;          // B frags: [ks(2)][nt(6)][lane(64)]
    float* P  = (float*)smem;        // epilogue: [row(128)][97]

    const float* xc = ws + OFF_XC;
    const s8v* A8 = (const s8v*)(ws + OFF_A);
    float* att = ws + OFF_ATT;

    int tid = threadIdx.x;
    int wave = tid >> 6, lane = tid & 63;
    int p0 = blockIdx.x * TPB;

    // builder role: 16 subtasks/pair = rblk(4) x dsel(4, 3 active)
    int pairL = tid >> 4;            // 0..31
    int sub = tid & 15;
    int rblk = sub >> 2;             // r0 = rblk*16
    int dsel = sub & 3;              // 0..2 = d, 3 = idle
    int pairG = p0 + pairL;
    int bb = pairG >> 10, gg = pairG & 1023;
    const float* xp = xc + ((size_t)bb * 8192 + gg * 8) * 3;

    f4v acc[2][6];
#pragma unroll
    for (int mi = 0; mi < 2; ++mi)
#pragma unroll
        for (int nt = 0; nt < 6; ++nt) acc[mi][nt] = (f4v)0.f;

#pragma unroll 1
    for (int pp = 0; pp < 28; ++pp) {
        // A prefetch (mtiles wave, wave+8), consumed after LBAR
        s8v afr[2][2];
#pragma unroll
        for (int ksl = 0; ksl < 2; ++ksl) {
            afr[ksl][0] = A8[((pp*2 + ksl)*16 + wave    )*64 + lane];
            afr[ksl][1] = A8[((pp*2 + ksl)*16 + wave + 8)*64 + lane];
        }

        // ---- B build ----
        if (dsel < 3) {
            int i = c_pi[pp], j = c_pj[pp];
            float dx = xp[j*3+0] - xp[i*3+0];
            float dy = xp[j*3+1] - xp[i*3+1];
            float dz = xp[j*3+2] - xp[i*3+2];
            float dn = sqrtf(dx*dx + dy*dy + dz*dz + 1e-5f);
            float pref = 0.f;
            if (dn < 5.0f) pref = 0.5f * (cosf(dn * 0.62831853071795865f) + 1.0f);
            float dinv = dn + 1e-5f;
            pref /= (dinv * dinv);
            float ex = expf(-dn);
            int r0 = rblk * 16;
            float d0 = ex - (M0_ + (float)r0 * STEP_);
            float sm    = pref * expf(-BETA_ * d0 * d0);
            float ratio = expf(C2_ * d0 - C3_);
            float smv[16];
#pragma unroll
            for (int q = 0; q < 16; ++q) { smv[q] = sm; sm *= ratio; ratio *= BC_; }
            float dd = (dsel == 0) ? dx : (dsel == 1) ? dy : dz;
            int col = pairL * 3 + dsel;
            int nt = col >> 4, cl = col & 15;
#pragma unroll
            for (int half = 0; half < 2; ++half) {
                int rb = r0 + half * 8;
                int ks = rb >> 5;
                int lf = (((rb >> 3) & 3) << 4) | cl;
                s8v v;
#pragma unroll
                for (int e = 0; e < 8; ++e)
                    v[e] = (short)f2bf(smv[half*8 + e] * dd);
                Bf[(ks*6 + nt)*64 + lf] = v;
            }
        }
        LBAR();

        // ---- MFMA ----
#pragma unroll
        for (int ksl = 0; ksl < 2; ++ksl)
#pragma unroll
            for (int nt = 0; nt < 6; ++nt) {
                s8v bfr = Bf[(ksl*6 + nt)*64 + lane];
#pragma unroll
                for (int mi = 0; mi < 2; ++mi)
                    acc[mi][nt] = __builtin_amdgcn_mfma_f32_16x16x32_bf16(
                        afr[ksl][mi], bfr, acc[mi][nt], 0, 0, 0);
            }
        LBAR();
    }

    // ---- epilogue ----
    // step 1+2 (wave-local rows w*16..w*16+15): write LEFT, multiply RIGHT
#pragma unroll
    for (int nt = 0; nt < 6; ++nt)
#pragma unroll
        for (int reg = 0; reg < 4; ++reg) {
            int row = wave*16 + (lane >> 4)*4 + reg;
            int col = nt*16 + (lane & 15);
            P[row*97 + col] = acc[0][nt][reg];
        }
#pragma unroll
    for (int nt = 0; nt < 6; ++nt)
#pragma unroll
        for (int reg = 0; reg < 4; ++reg) {
            int row = wave*16 + (lane >> 4)*4 + reg;
            int col = nt*16 + (lane & 15);
            P[row*97 + col] *= acc[1][nt][reg];
        }
    __syncthreads();
    // step 3: att = sum of 3 cols
    int h = tid & 127;
    int pr0 = (tid >> 7) * 8;
#pragma unroll
    for (int q = 0; q < 8; ++q) {
        int pr = pr0 + q;
        float a = P[h*97 + pr*3] + P[h*97 + pr*3 + 1] + P[h*97 + pr*3 + 2] + 1e-5f;
        att[(size_t)(p0 + pr) * 128 + h] = a;
    }
}

// K3: partial online logsumexp. 256 blocks = (b, gblk of 32 g).
__global__ __launch_bounds__(256) void k_lse(float* __restrict__ ws) {
    const float* att = ws + OFF_ATT;
    float* part = ws + OFF_PART;
    int blk = blockIdx.x;
    int b = blk >> 5, gblk = blk & 31;
    int tid = threadIdx.x;
    int h = tid & 127, gh = tid >> 7;
    const float* p = att + ((size_t)(b*1024 + gblk*32 + gh*16))*128 + h;
    float m = -1e30f, s = 0.f;
#pragma unroll
    for (int q = 0; q < 16; ++q) {
        float v = p[(size_t)q * 128];
        float nm = fmaxf(m, v);
        s = s * expf(m - nm) + expf(v - nm);
        m = nm;
    }
    __shared__ float mm[256], ss[256];
    mm[tid] = m; ss[tid] = s;
    __syncthreads();
    if (gh == 0) {
        float m2 = mm[tid + 128], s2 = ss[tid + 128];
        float Mv = fmaxf(m, m2);
        float Sv = s * expf(m - Mv) + s2 * expf(m2 - Mv);
        *(float2*)&part[((size_t)(b*32 + gblk)*128 + h)*2] = make_float2(Mv, Sv);
    }
}

// K4: combine 32 partials -> lse[b][h], then fc1+silu+fc2 -> out[b].
__global__ __launch_bounds__(128) void k_mlp(const float* __restrict__ ws,
                                             const float* __restrict__ f1w,
                                             const float* __restrict__ f1b,
                                             const float* __restrict__ f2w,
                                             const float* __restrict__ f2b,
                                             float* __restrict__ out) {
    const float* part = ws + OFF_PART;
    int b = blockIdx.x, h = threadIdx.x;
    float Mv = -1e30f, Sv = 0.f;
#pragma unroll
    for (int k = 0; k < 32; ++k) {
        float2 v = *(const float2*)&part[((size_t)(b*32 + k)*128 + h)*2];
        float nm = fmaxf(Mv, v.x);
        Sv = Sv * expf(Mv - nm) + v.y * expf(v.x - nm);
        Mv = nm;
    }
    float lse = Mv + logf(Sv);
    __shared__ float ls[128];
    ls[h] = lse;
    __syncthreads();
    float acc = f1b[h];
    for (int k = 0; k < 128; ++k) acc += f1w[h*128 + k] * ls[k];
    float v = acc / (1.f + expf(-acc));     // silu
    __shared__ float red[128];
    red[h] = v * f2w[h];
    __syncthreads();
    for (int st = 64; st > 0; st >>= 1) {
        if (h < st) red[h] += red[h + st];
        __syncthreads();
    }
    if (h == 0) out[b] = red[0] + f2b[0];
}

extern "C" void kernel_launch(void* const* d_in, const int* in_sizes, int n_in,
                              void* d_out, int out_size, void* d_ws, size_t ws_size,
                              hipStream_t stream) {
    const float* x   = (const float*)d_in[0];
    const float* Wm  = (const float*)d_in[1];
    const float* Wl  = (const float*)d_in[2];
    const float* Wr  = (const float*)d_in[3];
    const float* f1w = (const float*)d_in[4];
    const float* f1b = (const float*)d_in[5];
    const float* f2w = (const float*)d_in[6];
    const float* f2b = (const float*)d_in[7];
    float* ws  = (float*)d_ws;
    float* out = (float*)d_out;

    k_folda<<<224, 256, 0, stream>>>(Wl, Wr, ws);
    k_xc   <<<512, 256, 0, stream>>>(x, Wm, ws);
    k_main <<<256, 512, 0, stream>>>(ws);
    k_lse  <<<256, 256, 0, stream>>>(ws);
    k_mlp  <<<8,   128, 0, stream>>>(ws, f1w, f1b, f2w, f2b, out);
}

// Round 6
// 208.523 us; speedup vs baseline: 3.9606x; 1.0745x over previous
//
#include <hip/hip_runtime.h>
#include <hip/hip_bf16.h>
#include <math.h>

#define B_   8
#define G_   1024
#define M_   8
#define N_   2048
#define RBF_ 50
#define H_   128
#define PP_  28      // i<j pairs of 8
#define RPP  64      // r padded per pp (2 MFMA K-steps); r>=50 -> A holds 0
#define KSTEPS (PP_*RPP/32)     // 56
#define TPB  32      // (b,g) pairs per k_main block -> N=96 cols

// ---- workspace layout (in floats) ----
#define OFF_A    0
#define SZ_A     (KSTEPS*16*64*8/2)        // 229376 floats (bf16 A frags)
#define OFF_XC   (OFF_A + SZ_A)            // 229376
#define SZ_XC    (B_*G_*M_*3)              // 196608
#define OFF_ATT  (OFF_XC + SZ_XC)          // 425984  (layout [b][g][h])
#define SZ_ATT   (B_*H_*G_)                // 1048576
#define OFF_PART (OFF_ATT + SZ_ATT)        // 1474560
#define SZ_PART  (B_*32*H_*2)              // 65536
#define OFF_XT   (OFF_PART + SZ_PART)      // 1540096  xT[24][2048]
#define SZ_XT    (24*N_)                   // 49152

// ExpNormal constants
#define M0_   0.006737946999085467f
#define STEP_ 0.020270858224508f
#define BETA_ 633.5087862829640f
#define C2_   25.68448448181152f           // 2*BETA*STEP
#define C3_   0.26031300425529f            // BETA*STEP^2
#define BC_   0.59416621404589f            // exp(-2*BETA*STEP^2)

typedef __attribute__((ext_vector_type(8))) short s8v;   // 8 bf16
typedef __attribute__((ext_vector_type(4))) float f4v;

// lgkmcnt-only barrier: LDS producer/consumer sync WITHOUT draining vmcnt,
// so global load streams survive across it (no global_load_lds used).
#define LBAR() do { \
    asm volatile("s_waitcnt lgkmcnt(0)\n\ts_barrier" ::: "memory"); \
    __builtin_amdgcn_sched_barrier(0); \
} while (0)

__device__ const int c_pi[28] = {0,0,0,0,0,0,0,1,1,1,1,1,1,2,2,2,2,2,3,3,3,3,4,4,4,5,5,6};
__device__ const int c_pj[28] = {1,2,3,4,5,6,7,2,3,4,5,6,7,3,4,5,6,7,4,5,6,7,5,6,7,6,7,7};

__device__ __forceinline__ unsigned short f2bf(float f) {   // RNE f32->bf16
    unsigned int b = __float_as_uint(f);
    return (unsigned short)((b + 0x7FFFu + ((b >> 16) & 1u)) >> 16);
}

// K-2: transpose x[b][n][d] -> xT[c=b*3+d][n] (196 KB, one-time, L2-hot after)
__global__ __launch_bounds__(256) void k_xt(const float* __restrict__ x,
                                            float* __restrict__ ws) {
    int idx = blockIdx.x * 256 + threadIdx.x;   // 49152 exact
    int c = idx >> 11, n = idx & 2047;
    int b = c / 3, d = c - b * 3;
    ws[OFF_XT + idx] = x[b * 6144 + n * 3 + d];
}

// K0: folded weights in MFMA A-fragment order, bf16 (unchanged from r4).
__global__ __launch_bounds__(256) void k_folda(const float* __restrict__ Wl,
                                               const float* __restrict__ Wr,
                                               float* __restrict__ ws) {
    int t = blockIdx.x * 256 + threadIdx.x;   // 57344 tasks
    int lane = t & 63;
    int mt = (t >> 6) & 15;
    int kstep = t >> 10;                      // 0..55
    int pp = kstep >> 1;
    int row = mt * 16 + (lane & 15);
    int side = row >> 7, h = row & 127;
    int r0 = (kstep & 1) * 32 + (lane >> 4) * 8;
    int i = c_pi[pp], j = c_pj[pp];
    const float* src = side ? Wr : Wl;
    const float* pij = src + h * 3200 + (i * 8 + j) * 50;
    const float* pji = src + h * 3200 + (j * 8 + i) * 50;
    s8v v;
#pragma unroll
    for (int e = 0; e < 8; ++e) {
        int r = r0 + e;
        float f = (r < 50) ? (pij[r] - pji[r]) : 0.f;
        v[e] = (short)f2bf(f);
    }
    ((s8v*)(ws + OFF_A))[t] = v;
}

// K1 v3: xc[b,row,d] = sum_n W[row,n]*xT[c,n]. 512 blocks = 128 rowgroups
// (64 rows) x 4 K-slices (512 k). Thread = (row=lane, wave=k-quarter),
// acc[24] only -> no spill. W_s[64][65]: staged coalesced, compute-read
// 2-way-free b32; x_s[64][28]: wave-uniform b128 broadcasts. Double-buffered
// LDS, reg prefetch, one lgkm-barrier per chunk; W global stream never
// drained. Epilogue: cross-wave LDS reduce -> one atomicAdd per (row,c,slice).
__global__ __launch_bounds__(256, 4) void k_xc(const float* __restrict__ Wm,
                                               float* __restrict__ ws) {
    __shared__ __align__(16) float W_s[2][64][65];   // 33280 B
    __shared__ __align__(16) float x_s[2][64][28];   // 14336 B
    const float* xT = ws + OFF_XT;
    float* xc = ws + OFF_XC;

    int tid = threadIdx.x;
    int lane = tid & 63, wq = tid >> 6;
    int rowbase = (blockIdx.x >> 2) * 64;
    int ks = blockIdx.x & 3;
    int kb0 = ks * 512;

    int srow = tid >> 4, sk4 = tid & 15;     // W staging coords
    int skk = tid & 63, scs = tid >> 6;      // x staging coords

    float acc[24];
#pragma unroll
    for (int c = 0; c < 24; ++c) acc[c] = 0.f;

    // stage chunk 0
#pragma unroll
    for (int i = 0; i < 4; ++i)
        *(float4*)&W_s[0][i*16 + srow][sk4*4] =
            *(const float4*)&Wm[(size_t)(rowbase + i*16 + srow)*2048 + kb0 + sk4*4];
#pragma unroll
    for (int q = 0; q < 6; ++q)
        x_s[0][skk][scs*6 + q] = xT[(scs*6 + q)*2048 + kb0 + skk];
    LBAR();

#pragma unroll 1
    for (int nc = 0; nc < 8; ++nc) {
        int cur = nc & 1;
        float4 wpf[4];
        float xpf[6];
        if (nc < 7) {
            int kb = kb0 + (nc + 1) * 64;
#pragma unroll
            for (int i = 0; i < 4; ++i)
                wpf[i] = *(const float4*)&Wm[(size_t)(rowbase + i*16 + srow)*2048 + kb + sk4*4];
#pragma unroll
            for (int q = 0; q < 6; ++q)
                xpf[q] = xT[(scs*6 + q)*2048 + kb + skk];
        }
        // compute on buffer cur
#pragma unroll
        for (int k = 0; k < 16; ++k) {
            int kk = wq * 16 + k;
            float w = W_s[cur][lane][kk];
            float4 xv0 = *(const float4*)&x_s[cur][kk][0];
            float4 xv1 = *(const float4*)&x_s[cur][kk][4];
            float4 xv2 = *(const float4*)&x_s[cur][kk][8];
            float4 xv3 = *(const float4*)&x_s[cur][kk][12];
            float4 xv4 = *(const float4*)&x_s[cur][kk][16];
            float4 xv5 = *(const float4*)&x_s[cur][kk][20];
            acc[0]  += w*xv0.x; acc[1]  += w*xv0.y; acc[2]  += w*xv0.z; acc[3]  += w*xv0.w;
            acc[4]  += w*xv1.x; acc[5]  += w*xv1.y; acc[6]  += w*xv1.z; acc[7]  += w*xv1.w;
            acc[8]  += w*xv2.x; acc[9]  += w*xv2.y; acc[10] += w*xv2.z; acc[11] += w*xv2.w;
            acc[12] += w*xv3.x; acc[13] += w*xv3.y; acc[14] += w*xv3.z; acc[15] += w*xv3.w;
            acc[16] += w*xv4.x; acc[17] += w*xv4.y; acc[18] += w*xv4.z; acc[19] += w*xv4.w;
            acc[20] += w*xv5.x; acc[21] += w*xv5.y; acc[22] += w*xv5.z; acc[23] += w*xv5.w;
        }
        if (nc < 7) {
            int nxt = cur ^ 1;
#pragma unroll
            for (int i = 0; i < 4; ++i)
                *(float4*)&W_s[nxt][i*16 + srow][sk4*4] = wpf[i];
#pragma unroll
            for (int q = 0; q < 6; ++q)
                x_s[nxt][skk][scs*6 + q] = xpf[q];
            LBAR();
        }
    }

    // cross-wave reduce via LDS overlay on W_s: red[wq][row][25]
    LBAR();                                   // all LDS reads done
    float* red = &W_s[0][0][0];               // 4*64*25 = 6400 floats
#pragma unroll
    for (int c = 0; c < 24; ++c)
        red[(wq*64 + lane)*25 + c] = acc[c];
    LBAR();
    int row = tid & 63, c6 = tid >> 6;
#pragma unroll
    for (int q = 0; q < 6; ++q) {
        int c = c6 * 6 + q;
        float s = red[(0*64 + row)*25 + c] + red[(1*64 + row)*25 + c]
                + red[(2*64 + row)*25 + c] + red[(3*64 + row)*25 + c];
        int b = c / 3, d = c - b * 3;
        atomicAdd(&xc[(size_t)b*24576 + (rowbase + row)*3 + d], s);
    }
}

// K2: MFMA main, 8 waves, 32 pairs, N=96. Per-pp critical path minimized:
// pair's 8 xc points live in 24 VGPRs (loaded once), constexpr i/j tables
// (pp loop fully unrolled), A-frags pipelined one pp ahead, double-buffered
// Bf with a single lgkm-barrier per pp.
__global__ __launch_bounds__(512, 2) void k_main(float* __restrict__ ws) {
    __shared__ __align__(16) char smem[128 * 97 * 4];   // 49664 B
    s8v*   Bf = (s8v*)smem;          // [buf(2)][ks(2)*6+nt][lane] -> 24576 B
    float* P  = (float*)smem;        // epilogue overlay: [row(128)][97]

    const float* xc = ws + OFF_XC;
    const s8v* A8 = (const s8v*)(ws + OFF_A);
    float* att = ws + OFF_ATT;

    constexpr int pi[28] = {0,0,0,0,0,0,0,1,1,1,1,1,1,2,2,2,2,2,3,3,3,3,4,4,4,5,5,6};
    constexpr int pj[28] = {1,2,3,4,5,6,7,2,3,4,5,6,7,3,4,5,6,7,4,5,6,7,5,6,7,6,7,7};

    int tid = threadIdx.x;
    int wave = tid >> 6, lane = tid & 63;
    int p0 = blockIdx.x * TPB;

    int pairL = tid >> 4;            // 0..31
    int sub = tid & 15;
    int rblk = sub >> 2;             // r0 = rblk*16
    int dsel = sub & 3;              // 0..2 = d, 3 = idle
    int pairG = p0 + pairL;

    // pair's 8 coarse points -> 24 registers
    float pts[24];
    {
        const float4* xq = (const float4*)(xc + (size_t)pairG * 24);
#pragma unroll
        for (int q = 0; q < 6; ++q) {
            float4 v = xq[q];
            pts[q*4+0] = v.x; pts[q*4+1] = v.y; pts[q*4+2] = v.z; pts[q*4+3] = v.w;
        }
    }

    f4v acc[2][6];
#pragma unroll
    for (int mi = 0; mi < 2; ++mi)
#pragma unroll
        for (int nt = 0; nt < 6; ++nt) acc[mi][nt] = (f4v)0.f;

    // A prefetch for pp=0
    s8v afr[2][2], afn[2][2];
#pragma unroll
    for (int ksl = 0; ksl < 2; ++ksl) {
        afr[ksl][0] = A8[((0*2 + ksl)*16 + wave    )*64 + lane];
        afr[ksl][1] = A8[((0*2 + ksl)*16 + wave + 8)*64 + lane];
    }

#pragma unroll
    for (int pp = 0; pp < 28; ++pp) {
        s8v* Bq = Bf + (pp & 1) * 768;
        // ---- B build ----
        if (dsel < 3) {
            float dx = pts[pj[pp]*3+0] - pts[pi[pp]*3+0];
            float dy = pts[pj[pp]*3+1] - pts[pi[pp]*3+1];
            float dz = pts[pj[pp]*3+2] - pts[pi[pp]*3+2];
            float dn = sqrtf(dx*dx + dy*dy + dz*dz + 1e-5f);
            float pref = 0.f;
            if (dn < 5.0f) pref = 0.5f * (cosf(dn * 0.62831853071795865f) + 1.0f);
            float dinv = dn + 1e-5f;
            pref /= (dinv * dinv);
            float ex = expf(-dn);
            float d0 = ex - (M0_ + (float)(rblk*16) * STEP_);
            float sm    = pref * expf(-BETA_ * d0 * d0);
            float ratio = expf(C2_ * d0 - C3_);
            float smv[16];
#pragma unroll
            for (int q = 0; q < 16; ++q) { smv[q] = sm; sm *= ratio; ratio *= BC_; }
            float dd = (dsel == 0) ? dx : (dsel == 1) ? dy : dz;
            int col = pairL * 3 + dsel;
            int nt = col >> 4, cl = col & 15;
#pragma unroll
            for (int half = 0; half < 2; ++half) {
                int rb = rblk*16 + half * 8;
                int ksw = rb >> 5;
                int lf = (((rb >> 3) & 3) << 4) | cl;
                s8v v;
#pragma unroll
                for (int e = 0; e < 8; ++e)
                    v[e] = (short)f2bf(smv[half*8 + e] * dd);
                Bq[(ksw*6 + nt)*64 + lf] = v;
            }
        }
        // A prefetch for pp+1 (in flight across the barrier)
        if (pp < 27) {
#pragma unroll
            for (int ksl = 0; ksl < 2; ++ksl) {
                afn[ksl][0] = A8[(((pp+1)*2 + ksl)*16 + wave    )*64 + lane];
                afn[ksl][1] = A8[(((pp+1)*2 + ksl)*16 + wave + 8)*64 + lane];
            }
        }
        LBAR();
        // ---- MFMA ----
#pragma unroll
        for (int ksl = 0; ksl < 2; ++ksl)
#pragma unroll
            for (int nt = 0; nt < 6; ++nt) {
                s8v bfr = Bq[(ksl*6 + nt)*64 + lane];
#pragma unroll
                for (int mi = 0; mi < 2; ++mi)
                    acc[mi][nt] = __builtin_amdgcn_mfma_f32_16x16x32_bf16(
                        afr[ksl][mi], bfr, acc[mi][nt], 0, 0, 0);
            }
#pragma unroll
        for (int ksl = 0; ksl < 2; ++ksl) {
            afr[ksl][0] = afn[ksl][0];
            afr[ksl][1] = afn[ksl][1];
        }
    }

    LBAR();                          // Bf dead; P overlay safe
    // ---- epilogue: wave-local rows w*16..w*16+15 ----
#pragma unroll
    for (int nt = 0; nt < 6; ++nt)
#pragma unroll
        for (int reg = 0; reg < 4; ++reg) {
            int row = wave*16 + (lane >> 4)*4 + reg;
            int col = nt*16 + (lane & 15);
            P[row*97 + col] = acc[0][nt][reg];
        }
#pragma unroll
    for (int nt = 0; nt < 6; ++nt)
#pragma unroll
        for (int reg = 0; reg < 4; ++reg) {
            int row = wave*16 + (lane >> 4)*4 + reg;
            int col = nt*16 + (lane & 15);
            P[row*97 + col] *= acc[1][nt][reg];
        }
    __syncthreads();
    int h = tid & 127;
    int pr0 = (tid >> 7) * 8;
#pragma unroll
    for (int q = 0; q < 8; ++q) {
        int pr = pr0 + q;
        float a = P[h*97 + pr*3] + P[h*97 + pr*3 + 1] + P[h*97 + pr*3 + 2] + 1e-5f;
        att[(size_t)(p0 + pr) * 128 + h] = a;
    }
}

// K3: partial online logsumexp. 256 blocks = (b, gblk of 32 g).
__global__ __launch_bounds__(256) void k_lse(float* __restrict__ ws) {
    const float* att = ws + OFF_ATT;
    float* part = ws + OFF_PART;
    int blk = blockIdx.x;
    int b = blk >> 5, gblk = blk & 31;
    int tid = threadIdx.x;
    int h = tid & 127, gh = tid >> 7;
    const float* p = att + ((size_t)(b*1024 + gblk*32 + gh*16))*128 + h;
    float m = -1e30f, s = 0.f;
#pragma unroll
    for (int q = 0; q < 16; ++q) {
        float v = p[(size_t)q * 128];
        float nm = fmaxf(m, v);
        s = s * expf(m - nm) + expf(v - nm);
        m = nm;
    }
    __shared__ float mm[256], ss[256];
    mm[tid] = m; ss[tid] = s;
    __syncthreads();
    if (gh == 0) {
        float m2 = mm[tid + 128], s2 = ss[tid + 128];
        float Mv = fmaxf(m, m2);
        float Sv = s * expf(m - Mv) + s2 * expf(m2 - Mv);
        *(float2*)&part[((size_t)(b*32 + gblk)*128 + h)*2] = make_float2(Mv, Sv);
    }
}

// K4: combine 32 partials -> lse[b][h], then fc1+silu+fc2 -> out[b].
__global__ __launch_bounds__(128) void k_mlp(const float* __restrict__ ws,
                                             const float* __restrict__ f1w,
                                             const float* __restrict__ f1b,
                                             const float* __restrict__ f2w,
                                             const float* __restrict__ f2b,
                                             float* __restrict__ out) {
    const float* part = ws + OFF_PART;
    int b = blockIdx.x, h = threadIdx.x;
    float Mv = -1e30f, Sv = 0.f;
#pragma unroll
    for (int k = 0; k < 32; ++k) {
        float2 v = *(const float2*)&part[((size_t)(b*32 + k)*128 + h)*2];
        float nm = fmaxf(Mv, v.x);
        Sv = Sv * expf(Mv - nm) + v.y * expf(v.x - nm);
        Mv = nm;
    }
    float lse = Mv + logf(Sv);
    __shared__ float ls[128];
    ls[h] = lse;
    __syncthreads();
    float acc = f1b[h];
    for (int k = 0; k < 128; ++k) acc += f1w[h*128 + k] * ls[k];
    float v = acc / (1.f + expf(-acc));     // silu
    __shared__ float red[128];
    red[h] = v * f2w[h];
    __syncthreads();
    for (int st = 64; st > 0; st >>= 1) {
        if (h < st) red[h] += red[h + st];
        __syncthreads();
    }
    if (h == 0) out[b] = red[0] + f2b[0];
}

extern "C" void kernel_launch(void* const* d_in, const int* in_sizes, int n_in,
                              void* d_out, int out_size, void* d_ws, size_t ws_size,
                              hipStream_t stream) {
    const float* x   = (const float*)d_in[0];
    const float* Wm  = (const float*)d_in[1];
    const float* Wl  = (const float*)d_in[2];
    const float* Wr  = (const float*)d_in[3];
    const float* f1w = (const float*)d_in[4];
    const float* f1b = (const float*)d_in[5];
    const float* f2w = (const float*)d_in[6];
    const float* f2b = (const float*)d_in[7];
    float* ws  = (float*)d_ws;
    float* out = (float*)d_out;

    hipMemsetAsync(ws + OFF_XC, 0, SZ_XC * sizeof(float), stream);
    k_xt   <<<192, 256, 0, stream>>>(x, ws);
    k_folda<<<224, 256, 0, stream>>>(Wl, Wr, ws);
    k_xc   <<<512, 256, 0, stream>>>(Wm, ws);
    k_main <<<256, 512, 0, stream>>>(ws);
    k_lse  <<<256, 256, 0, stream>>>(ws);
    k_mlp  <<<8,   128, 0, stream>>>(ws, f1w, f1b, f2w, f2b, out);
}